// Round 2
// baseline (260.783 us; speedup 1.0000x reference)
//
#include <hip/hip_runtime.h>

// PhotometricLoss: fused warp + SSIM(3x3 avgpool, zero-pad) + L1 + masked mean.
// B=8, C=3, H=720, W=1280 fp32.
//
// R5: occupancy + I-footprint attack (R4's manual pipeline restructure was a
// no-op: fully-unrolled 24KB body -> compiler schedules globally; measured
// 103us / 40% VALUBusy / 36% occ both rounds -> latency-bound at ~3 waves/SIMD,
// residency capped by combined VGPR+AGPR of the 45-reg ring at bounds(256,4)).
//  1. 2-slot stat ring (emit center r-1 as soon as row r stats exist):
//     30 persistent ring regs instead of 45 (+2 l1/valid history).
//  2. Rolled loop, #pragma unroll 2, named ring vars (shift renames away in
//     the unrolled pair): ~1.5KB body instead of 24KB -> no L1I pressure.
//  3. __launch_bounds__(256,6): 85-reg budget -> 24 waves/CU target.
// Load pipeline depth kept at 1 full step (gathers for r+1 + left(r+1) +
// disp(r+2) issued at step r), same as R4 but now carried by the rolled loop.

#define P_ALPHA 0.85f
#define P_C1 1e-4f
#define P_C2 9e-4f

constexpr int COLS  = 62;   // useful output columns per wave strip
constexpr int RPW   = 15;   // output rows per wave (720 = 12*4*15)
constexpr int WAVES = 4;    // waves per block

__global__ __launch_bounds__(256, 6)
void photo_loss_kernel(const float* __restrict__ disp,
                       const float* __restrict__ left,
                       const float* __restrict__ right,
                       float* __restrict__ acc,   // acc[0]=sum(photo*valid), acc[1]=sum(valid)
                       int H, int W)
{
    __shared__ float redpv[WAVES];
    __shared__ float redv[WAVES];

    const int tid  = threadIdx.x;
    const int lane = tid & 63;
    const int w    = tid >> 6;
    const int b    = blockIdx.z;
    const int col  = blockIdx.x * COLS + lane - 1;          // -1 .. W (+halo)
    const int rowStart = (blockIdx.y * WAVES + w) * RPW;

    const int planeHW = H * W;
    const float* __restrict__ dispb = disp  + b * planeHW;
    const float* __restrict__ L0 = left  + (b * 3 + 0) * planeHW;
    const float* __restrict__ L1 = left  + (b * 3 + 1) * planeHW;
    const float* __restrict__ L2 = left  + (b * 3 + 2) * planeHW;
    const float* __restrict__ R0 = right + (b * 3 + 0) * planeHW;
    const float* __restrict__ R1 = right + (b * 3 + 1) * planeHW;
    const float* __restrict__ R2 = right + (b * 3 + 2) * planeHW;

    const float wm1f = (float)(W - 1);
    const int   colC = min(max(col, 0), W - 1);             // clamped address col
    const float colv = (col >= 0 && col < W) ? 1.f : 0.f;   // column validity
    const float ocm  = (lane >= 1 && lane <= COLS && col < W) ? 1.f : 0.f;  // output mask

    // 2-slot named ring: A = h[r-2], B = h[r-1]  (5 stats x 3 channels x 2)
    float Ax0=0.f,Ay0=0.f,Axx0=0.f,Ayy0=0.f,Axy0=0.f;
    float Ax1=0.f,Ay1=0.f,Axx1=0.f,Ayy1=0.f,Axy1=0.f;
    float Ax2=0.f,Ay2=0.f,Axx2=0.f,Ayy2=0.f,Axy2=0.f;
    float Bx0=0.f,By0=0.f,Bxx0=0.f,Byy0=0.f,Bxy0=0.f;
    float Bx1=0.f,By1=0.f,Bxx1=0.f,Byy1=0.f,Bxy1=0.f;
    float Bx2=0.f,By2=0.f,Bxx2=0.f,Byy2=0.f,Bxy2=0.f;
    float l1P=0.f, vP=0.f;                  // l1/valid of row r-1 (center at emit)

    float sum_pv = 0.f, sum_v = 0.f;

    // ---- pipeline registers: loads for the row consumed NEXT step ----
    float gN0,gN1,gN2,gN3,gN4,gN5, frN, vmN, xN0,xN1,xN2;
    float dN;                               // disp for the row AFTER that
    int   offN;                             // its clamped linear offset

    {   // prologue: prefetch row rowStart-1 (consumed at j=0); disp of rowStart
        const int   rc0  = max(rowStart - 1, 0);
        const int   off0 = rc0 * W + colC;
        const float d0   = dispb[off0];
        xN0 = L0[off0]; xN1 = L1[off0]; xN2 = L2[off0];
        offN = rowStart * W + colC;          // rowStart always in [0,H)
        dN   = dispb[offN];
        const float xs  = (float)col - d0;
        const float xcl = fminf(fmaxf(xs, 0.f), wm1f);
        const float xf  = floorf(xcl);
        frN = xcl - xf;
        const int i0 = (int)xf;
        const int i1 = min(i0 + 1, W - 1);
        const int ro = rc0 * W;
        gN0 = R0[ro + i0]; gN1 = R0[ro + i1];
        gN2 = R1[ro + i0]; gN3 = R1[ro + i1];
        gN4 = R2[ro + i0]; gN5 = R2[ro + i1];
        vmN = (xs > 0.f && xs < wm1f) ? 1.f : 0.f;
    }

    #pragma unroll 2
    for (int j = 0; j < RPW + 2; ++j) {
        const int r = rowStart - 1 + j;      // row consumed this step

        // take this step's in-flight values (pure renames)
        const float g0=gN0,g1=gN1,g2=gN2,g3=gN3,g4=gN4,g5=gN5;
        const float fr=frN, vm=vmN, xc0=xN0, xc1=xN1, xc2=xN2;

        // ---- issue next step's loads (row r+1 gathers, left r+1, disp r+2) ----
        if (j <= RPW) {                      // wave-uniform branch
            const float xs  = (float)col - dN;
            const float xcl = fminf(fmaxf(xs, 0.f), wm1f);
            const float xf  = floorf(xcl);
            frN = xcl - xf;
            const int i0 = (int)xf;
            const int i1 = min(i0 + 1, W - 1);
            const int ro = offN - colC;      // = clamp(r+1)*W
            gN0 = R0[ro + i0]; gN1 = R0[ro + i1];
            gN2 = R1[ro + i0]; gN3 = R1[ro + i1];
            gN4 = R2[ro + i0]; gN5 = R2[ro + i1];
            vmN = (xs > 0.f && xs < wm1f) ? 1.f : 0.f;
            xN0 = L0[offN]; xN1 = L1[offN]; xN2 = L2[offN];
            const int rc2 = min(r + 2, H - 1);   // r+2 >= 1 always
            offN = rc2 * W + colC;
            dN   = dispb[offN];
        }

        // ---- compute row-r horizontal stats (hC) ----
        const float rv  = (r >= 0 && r < H) ? 1.f : 0.f;
        const float m   = rv * colv;
        const float omf = 1.f - fr;
        const float y0 = (omf * g0 + fr * g1) * m;
        const float y1 = (omf * g2 + fr * g3) * m;
        const float y2 = (omf * g4 + fr * g5) * m;
        const float x0 = xc0 * m;
        const float x1 = xc1 * m;
        const float x2 = xc2 * m;

        float Cx0,Cy0,Cxx0,Cyy0,Cxy0;
        float Cx1,Cy1,Cxx1,Cyy1,Cxy1;
        float Cx2,Cy2,Cxx2,Cyy2,Cxy2;
        {
            const float xl = __shfl_up(x0,1,64), xr = __shfl_down(x0,1,64);
            const float yl = __shfl_up(y0,1,64), yr = __shfl_down(y0,1,64);
            Cx0  = xl + x0 + xr;
            Cy0  = yl + y0 + yr;
            Cxx0 = xl*xl + x0*x0 + xr*xr;
            Cyy0 = yl*yl + y0*y0 + yr*yr;
            Cxy0 = xl*yl + x0*y0 + xr*yr;
        }
        {
            const float xl = __shfl_up(x1,1,64), xr = __shfl_down(x1,1,64);
            const float yl = __shfl_up(y1,1,64), yr = __shfl_down(y1,1,64);
            Cx1  = xl + x1 + xr;
            Cy1  = yl + y1 + yr;
            Cxx1 = xl*xl + x1*x1 + xr*xr;
            Cyy1 = yl*yl + y1*y1 + yr*yr;
            Cxy1 = xl*yl + x1*y1 + xr*yr;
        }
        {
            const float xl = __shfl_up(x2,1,64), xr = __shfl_down(x2,1,64);
            const float yl = __shfl_up(y2,1,64), yr = __shfl_down(y2,1,64);
            Cx2  = xl + x2 + xr;
            Cy2  = yl + y2 + yr;
            Cxx2 = xl*xl + x2*x2 + xr*xr;
            Cyy2 = yl*yl + y2*y2 + yr*yr;
            Cxy2 = xl*yl + x2*y2 + xr*yr;
        }
        const float l1C = fabsf(x0 - y0) + fabsf(x1 - y1) + fabsf(x2 - y2);
        const float vC  = vm;

        // ---- emit center r-1 using (A=h[r-2], B=h[r-1], C=h[r]) ----
        if (j >= 2) {                        // wave-uniform branch
            const float inv9 = 1.f / 9.f;
            float ssim_sum = 0.f;
            #define SSIM_CH(SX,SY,SXX,SYY,SXY)                                   \
            {                                                                    \
                const float mu_x = (A##SX + B##SX + C##SX) * inv9;               \
                const float mu_y = (A##SY + B##SY + C##SY) * inv9;               \
                const float exx  = (A##SXX + B##SXX + C##SXX) * inv9;            \
                const float eyy  = (A##SYY + B##SYY + C##SYY) * inv9;            \
                const float exy  = (A##SXY + B##SXY + C##SXY) * inv9;            \
                const float sig_x  = fmaxf(exx - mu_x * mu_x, 0.f);              \
                const float sig_y  = fmaxf(eyy - mu_y * mu_y, 0.f);              \
                const float sig_xy = exy - mu_x * mu_y;                          \
                const float n  = (2.f*mu_x*mu_y + P_C1) * (2.f*sig_xy + P_C2);   \
                const float dd = (mu_x*mu_x + mu_y*mu_y + P_C1)                  \
                               * (sig_x + sig_y + P_C2);                         \
                float s = (1.f - n * __builtin_amdgcn_rcpf(dd)) * 0.5f;          \
                s = fminf(fmaxf(s, 0.f), 1.f);                                   \
                ssim_sum += s;                                                   \
            }
            SSIM_CH(x0,y0,xx0,yy0,xy0)
            SSIM_CH(x1,y1,xx1,yy1,xy1)
            SSIM_CH(x2,y2,xx2,yy2,xy2)
            #undef SSIM_CH
            const float photo = P_ALPHA * (ssim_sum * (1.f / 3.f))
                              + (1.f - P_ALPHA) * (l1P * (1.f / 3.f));
            sum_pv += photo * vP * ocm;
            sum_v  += vP * ocm;
        }

        // ---- ring shift (renamed away inside the unroll-2 pair) ----
        Ax0=Bx0; Ay0=By0; Axx0=Bxx0; Ayy0=Byy0; Axy0=Bxy0;
        Ax1=Bx1; Ay1=By1; Axx1=Bxx1; Ayy1=Byy1; Axy1=Bxy1;
        Ax2=Bx2; Ay2=By2; Axx2=Bxx2; Ayy2=Byy2; Axy2=Bxy2;
        Bx0=Cx0; By0=Cy0; Bxx0=Cxx0; Byy0=Cyy0; Bxy0=Cxy0;
        Bx1=Cx1; By1=Cy1; Bxx1=Cxx1; Byy1=Cyy1; Bxy1=Cxy1;
        Bx2=Cx2; By2=Cy2; Bxx2=Cxx2; Byy2=Cyy2; Bxy2=Cxy2;
        l1P = l1C; vP = vC;
    }

    // wave reduce (64 lanes) then cross-wave via tiny LDS
    #pragma unroll
    for (int off = 32; off > 0; off >>= 1) {
        sum_pv += __shfl_down(sum_pv, off, 64);
        sum_v  += __shfl_down(sum_v,  off, 64);
    }
    if (lane == 0) { redpv[w] = sum_pv; redv[w] = sum_v; }
    __syncthreads();
    if (tid == 0) {
        atomicAdd(&acc[0], redpv[0] + redpv[1] + redpv[2] + redpv[3]);
        atomicAdd(&acc[1], redv[0]  + redv[1]  + redv[2]  + redv[3]);
    }
}

__global__ void photo_loss_finalize(const float* __restrict__ acc,
                                    float* __restrict__ out)
{
    out[0] = acc[0] / fmaxf(acc[1], 1.f);
}

extern "C" void kernel_launch(void* const* d_in, const int* in_sizes, int n_in,
                              void* d_out, int out_size, void* d_ws, size_t ws_size,
                              hipStream_t stream)
{
    const float* disp  = (const float*)d_in[0];
    const float* left  = (const float*)d_in[1];
    const float* right = (const float*)d_in[2];
    float* out = (float*)d_out;
    float* acc = (float*)d_ws;

    const int B = 8, H = 720, W = 1280;

    hipMemsetAsync(acc, 0, 2 * sizeof(float), stream);

    // x: 21 strips of 62 cols; y: 720 / (4 waves * 15 rows) = 12; z: batch
    dim3 grid((W + COLS - 1) / COLS, H / (WAVES * RPW), B);
    dim3 block(256);
    photo_loss_kernel<<<grid, block, 0, stream>>>(disp, left, right, acc, H, W);
    photo_loss_finalize<<<1, 1, 0, stream>>>(acc, out);
}